// Round 9
// baseline (207.636 us; speedup 1.0000x reference)
//
#include <hip/hip_runtime.h>
#include <math.h>

#define NB 16      // batch
#define NN 4096    // nodes
#define NE 65536   // edges
#define DD 256     // feature dim
#define NR 4       // relations (excl. self)
#define VG 30000
#define VS 20000
#define NTG 118    // ceil(7500/64) v4-tiles (64 float4 = 256 v per block)
#define NTS 79     // ceil(5000/64)
#define FTG 30     // ceil(VG/1024)
#define FTS 20     // ceil(VS/1024)
#define MCAP 1024

// ws layout (float offsets):
#define WS_MC   0       // mcount [NB] int                 (16)
#define WS_CNT  16      // cnt [NB][NR] int                (64)
#define WS_H0T  80      // h0accT [DD][NB] (pre-ReLU)      (4096)
#define WS_U    4176    // u [NB][NR+1][DD]                (20480)
#define WS_MAT  24656   // matches [NB][MCAP] int          (16384)
#define WS_PM   41040   // per-tile max partials           (3152)
#define WS_PS   44192   // per-tile sumexp partials        (3152)
// total 47344 floats ~= 190 KB; memset zeroes first 4176 (mc+cnt+h0accT)

__global__ __launch_bounds__(256) void k_scan(
    const int* __restrict__ ei, const int* __restrict__ etp,
    int* __restrict__ mcount, int* __restrict__ cnt, int* __restrict__ matches) {
  const int b = blockIdx.x;
  const int* src = ei + (size_t)b * 2 * NE;
  const int* dst = src + NE;
  const int* etb = etp + (size_t)b * NE;
  const int per = NE / gridDim.y;   // 4096
  const int base = blockIdx.y * per;
  for (int e0 = base + threadIdx.x * 4; e0 < base + per; e0 += blockDim.x * 4) {
    const int4 s = *reinterpret_cast<const int4*>(&src[e0]);
#pragma unroll
    for (int u = 0; u < 4; ++u) {
      const int sv = (u == 0) ? s.x : (u == 1) ? s.y : (u == 2) ? s.z : s.w;
      if (sv == 0) {
        const int e = e0 + u;
        const int r = etb[e];
        const int j = dst[e];
        atomicAdd(&cnt[b * NR + r], 1);
        const int idx = atomicAdd(&mcount[b], 1);
        if (idx < MCAP) matches[b * MCAP + idx] = (r << 12) | j;
      }
    }
  }
}

// grid NB: one block per graph. Match-parallel gather: all ~16 row loads are
// independent -> pipelined, not serial round trips.
__global__ __launch_bounds__(256) void k_u(
    const float* __restrict__ x, const int* __restrict__ mcount,
    const int* __restrict__ cnt, const int* __restrict__ matches,
    float* __restrict__ u) {
  const int b = blockIdx.x;
  const int tid = threadIdx.x;   // feature index k
  __shared__ int mloc[MCAP];
  const int n = min(mcount[b], MCAP);
  for (int i = tid; i < n; i += 256) mloc[i] = matches[b * MCAP + i];
  __syncthreads();
  float s0 = 0.f, s1 = 0.f, s2 = 0.f, s3 = 0.f;
  for (int m = 0; m < n; ++m) {
    const int mv = mloc[m];
    const int r = mv >> 12;
    const float v = x[((size_t)b * NN + (mv & 4095)) * DD + tid];
    if (r == 0) s0 += v;
    else if (r == 1) s1 += v;
    else if (r == 2) s2 += v;
    else s3 += v;
  }
  float* ub = u + (size_t)b * (NR + 1) * DD;
  ub[tid] = x[((size_t)b * NN) * DD + tid];   // self connection (W_all[0])
  ub[DD + tid]     = s0 * (1.f / fmaxf((float)cnt[b * NR + 0], 1.f));
  ub[2 * DD + tid] = s1 * (1.f / fmaxf((float)cnt[b * NR + 1], 1.f));
  ub[3 * DD + tid] = s2 * (1.f / fmaxf((float)cnt[b * NR + 2], 1.f));
  ub[4 * DD + tid] = s3 * (1.f / fmaxf((float)cnt[b * NR + 3], 1.f));
}

// grid (NR+1, 8): block (r, jt) computes u[:, r, :] @ W_all[r][:, jt*32..+32]
// for all 16 graphs; atomicAdd into h0accT[j][b]. W read once device-wide.
__global__ __launch_bounds__(256) void k_h0w(
    const float* __restrict__ W_all, const float* __restrict__ u,
    float* __restrict__ h0accT) {
  const int r = blockIdx.x;
  const int jt = blockIdx.y;
  const int tid = threadIdx.x;
  __shared__ float us[NB][DD];        // 16 KB
  __shared__ float red[8][NB][32];    // 16 KB
  {
    const float4* u4 = reinterpret_cast<const float4*>(u);
    float4* us4 = reinterpret_cast<float4*>(&us[0][0]);
    for (int i = tid; i < NB * 64; i += 256) {
      const int b = i >> 6, kf = i & 63;
      us4[i] = u4[((size_t)b * (NR + 1) + r) * 64 + kf];
    }
  }
  __syncthreads();
  const int jl = tid & 31;
  const int kg = tid >> 5;
  const int j = jt * 32 + jl;
  const float* W = W_all + (size_t)r * DD * DD + j;
  float acc[NB];
#pragma unroll
  for (int b = 0; b < NB; ++b) acc[b] = 0.f;
  const int kb = kg * 32;
  for (int k0 = 0; k0 < 32; k0 += 8) {
    float w[8];
#pragma unroll
    for (int q = 0; q < 8; ++q) w[q] = W[(size_t)(kb + k0 + q) * DD];
#pragma unroll
    for (int q = 0; q < 8; ++q) {
#pragma unroll
      for (int b = 0; b < NB; ++b)
        acc[b] = fmaf(us[b][kb + k0 + q], w[q], acc[b]);
    }
  }
#pragma unroll
  for (int b = 0; b < NB; ++b) red[kg][b][jl] = acc[b];
  __syncthreads();
  const int bh = tid >> 5;
#pragma unroll
  for (int half = 0; half < 2; ++half) {
    const int b = bh + half * 8;
    float s = 0.f;
#pragma unroll
    for (int g = 0; g < 8; ++g) s += red[g][b][jl];
    atomicAdd(&h0accT[j * NB + b], s);
  }
}

// grid NTG+NTS blocks of 1024 thr (16 waves). Block = 64 float4 columns.
// Wave w: kq = w>>1 (32 k), bq = w&1 (8 graphs). acc[8] float4 = 32 VGPR;
// 8-deep float4 W batches; W read exactly once; cross-wave reduce via
// conflict-free LDS atomicAdd; wave 0..3 do bias+store+softmax partials.
__global__ __launch_bounds__(1024, 2) void k_logits(
    const float* __restrict__ Wg, const float* __restrict__ bg,
    const float* __restrict__ Wss, const float* __restrict__ bs,
    const float* __restrict__ h0accT, float* __restrict__ out,
    float* __restrict__ pm, float* __restrict__ ps) {
  const int blk = blockIdx.x;
  int tile, V4, ntiles;
  const float *W, *bias;
  float *o, *pmh, *psh;
  if (blk < NTG) {
    tile = blk; V4 = VG / 4; W = Wg; bias = bg; o = out;
    pmh = pm; psh = ps; ntiles = NTG;
  } else {
    tile = blk - NTG; V4 = VS / 4; W = Wss; bias = bs; o = out + (size_t)NB * VG;
    pmh = pm + NB * NTG; psh = ps + NB * NTG; ntiles = NTS;
  }
  const int tid = threadIdx.x;
  __shared__ float4 hs4[DD][4];        // relu(h): [k][b-quad], 16 KB
  __shared__ float accumT[4][NB][64];  // [comp][graph][lane], 16 KB
  {
    float4 hv = reinterpret_cast<const float4*>(h0accT)[tid];  // tid = k*4+b4
    hv.x = fmaxf(hv.x, 0.f); hv.y = fmaxf(hv.y, 0.f);
    hv.z = fmaxf(hv.z, 0.f); hv.w = fmaxf(hv.w, 0.f);
    hs4[tid >> 2][tid & 3] = hv;
    reinterpret_cast<float4*>(&accumT[0][0][0])[tid] = make_float4(0.f, 0.f, 0.f, 0.f);
  }
  __syncthreads();

  const int w = tid >> 6;
  const int l = tid & 63;
  const int kq = w >> 1;   // 0..7
  const int bq = w & 1;    // 0..1
  const int v4 = tile * 64 + l;
  const bool valid = (v4 < V4);
  const int v4c = valid ? v4 : V4 - 1;
  const float4* W4 = reinterpret_cast<const float4*>(W) + v4c;

  float4 acc[8];
#pragma unroll
  for (int i = 0; i < 8; ++i) acc[i] = make_float4(0.f, 0.f, 0.f, 0.f);

  const int kbase = kq * 32;
#pragma unroll
  for (int c8 = 0; c8 < 4; ++c8) {
    const int kk = kbase + c8 * 8;
    float4 wv[8];
#pragma unroll
    for (int u = 0; u < 8; ++u) wv[u] = W4[(size_t)(kk + u) * V4];
    __builtin_amdgcn_sched_barrier(0);   // keep all 8 loads issued before FMAs
#pragma unroll
    for (int u = 0; u < 8; ++u) {
      const float4 ha = hs4[kk + u][bq * 2];
      const float4 hb = hs4[kk + u][bq * 2 + 1];
      acc[0].x = fmaf(wv[u].x, ha.x, acc[0].x); acc[0].y = fmaf(wv[u].y, ha.x, acc[0].y);
      acc[0].z = fmaf(wv[u].z, ha.x, acc[0].z); acc[0].w = fmaf(wv[u].w, ha.x, acc[0].w);
      acc[1].x = fmaf(wv[u].x, ha.y, acc[1].x); acc[1].y = fmaf(wv[u].y, ha.y, acc[1].y);
      acc[1].z = fmaf(wv[u].z, ha.y, acc[1].z); acc[1].w = fmaf(wv[u].w, ha.y, acc[1].w);
      acc[2].x = fmaf(wv[u].x, ha.z, acc[2].x); acc[2].y = fmaf(wv[u].y, ha.z, acc[2].y);
      acc[2].z = fmaf(wv[u].z, ha.z, acc[2].z); acc[2].w = fmaf(wv[u].w, ha.z, acc[2].w);
      acc[3].x = fmaf(wv[u].x, ha.w, acc[3].x); acc[3].y = fmaf(wv[u].y, ha.w, acc[3].y);
      acc[3].z = fmaf(wv[u].z, ha.w, acc[3].z); acc[3].w = fmaf(wv[u].w, ha.w, acc[3].w);
      acc[4].x = fmaf(wv[u].x, hb.x, acc[4].x); acc[4].y = fmaf(wv[u].y, hb.x, acc[4].y);
      acc[4].z = fmaf(wv[u].z, hb.x, acc[4].z); acc[4].w = fmaf(wv[u].w, hb.x, acc[4].w);
      acc[5].x = fmaf(wv[u].x, hb.y, acc[5].x); acc[5].y = fmaf(wv[u].y, hb.y, acc[5].y);
      acc[5].z = fmaf(wv[u].z, hb.y, acc[5].z); acc[5].w = fmaf(wv[u].w, hb.y, acc[5].w);
      acc[6].x = fmaf(wv[u].x, hb.z, acc[6].x); acc[6].y = fmaf(wv[u].y, hb.z, acc[6].y);
      acc[6].z = fmaf(wv[u].z, hb.z, acc[6].z); acc[6].w = fmaf(wv[u].w, hb.z, acc[6].w);
      acc[7].x = fmaf(wv[u].x, hb.w, acc[7].x); acc[7].y = fmaf(wv[u].y, hb.w, acc[7].y);
      acc[7].z = fmaf(wv[u].z, hb.w, acc[7].z); acc[7].w = fmaf(wv[u].w, hb.w, acc[7].w);
    }
  }

  // cross-wave reduce: conflict-free (lane -> consecutive banks), 8-way/addr
#pragma unroll
  for (int j = 0; j < 8; ++j) {
    const int g = bq * 8 + j;
    atomicAdd(&accumT[0][g][l], acc[j].x);
    atomicAdd(&accumT[1][g][l], acc[j].y);
    atomicAdd(&accumT[2][g][l], acc[j].z);
    atomicAdd(&accumT[3][g][l], acc[j].w);
  }
  __syncthreads();

  if (w < 4) {
    const float4 bb = reinterpret_cast<const float4*>(bias)[v4c];
    float4* o4 = reinterpret_cast<float4*>(o);
#pragma unroll
    for (int i = 0; i < 4; ++i) {
      const int g = w * 4 + i;
      float4 s;
      s.x = accumT[0][g][l] + bb.x;
      s.y = accumT[1][g][l] + bb.y;
      s.z = accumT[2][g][l] + bb.z;
      s.w = accumT[3][g][l] + bb.w;
      if (valid) o4[(size_t)g * V4 + v4] = s;
      float m = valid ? fmaxf(fmaxf(s.x, s.y), fmaxf(s.z, s.w)) : -INFINITY;
#pragma unroll
      for (int off = 32; off > 0; off >>= 1) m = fmaxf(m, __shfl_xor(m, off));
      float sx = valid ? (__expf(s.x - m) + __expf(s.y - m) +
                          __expf(s.z - m) + __expf(s.w - m)) : 0.f;
#pragma unroll
      for (int off = 32; off > 0; off >>= 1) sx += __shfl_xor(sx, off);
      if (l == 0) { pmh[g * ntiles + tile] = m; psh[g * ntiles + tile] = sx; }
    }
  }
}

// grid (FTG+FTS, NB): re-reduce tile partials to L, subtract from 1024-v slice.
__global__ __launch_bounds__(256) void k_fin(
    const float* __restrict__ pm, const float* __restrict__ ps,
    float* __restrict__ out) {
  const int b = blockIdx.y;
  int head, t;
  if ((int)blockIdx.x < FTG) { head = 0; t = blockIdx.x; }
  else { head = 1; t = blockIdx.x - FTG; }
  const int V = head ? VS : VG;
  const int ntiles = head ? NTS : NTG;
  const float* pmh = pm + (head ? NB * NTG : 0) + b * ntiles;
  const float* psh = ps + (head ? NB * NTG : 0) + b * ntiles;
  const int tid = threadIdx.x;
  const int vl = tid & 63;
  const int wid = tid >> 6;

  float m = -INFINITY, s = 0.f;
  if (tid < ntiles) { m = pmh[tid]; s = psh[tid]; }
#pragma unroll
  for (int off = 32; off > 0; off >>= 1) {
    float mo = __shfl_xor(m, off);
    float so = __shfl_xor(s, off);
    float Mn = fmaxf(m, mo);
    float sn = ((m > -INFINITY) ? s * __expf(m - Mn) : 0.f) +
               ((mo > -INFINITY) ? so * __expf(mo - Mn) : 0.f);
    m = Mn; s = sn;
  }
  __shared__ float lm[4], ls[4];
  __shared__ float Lsh;
  if (vl == 0) { lm[wid] = m; ls[wid] = s; }
  __syncthreads();
  if (tid == 0) {
    float M = -INFINITY, S = 0.f;
#pragma unroll
    for (int wv = 0; wv < 4; ++wv) {
      float mi = lm[wv], si = ls[wv];
      float Mn = fmaxf(M, mi);
      S = ((M > -INFINITY) ? S * __expf(M - Mn) : 0.f) +
          ((mi > -INFINITY) ? si * __expf(mi - Mn) : 0.f);
      M = Mn;
    }
    Lsh = M + logf(S);
  }
  __syncthreads();
  const float L = Lsh;
  float* o = out + (head ? (size_t)NB * VG : 0) + (size_t)b * V;
  const int v4 = t * 256 + tid;
  if (v4 * 4 < V) {
    float4* o4 = reinterpret_cast<float4*>(o);
    float4 x = o4[v4];
    x.x -= L; x.y -= L; x.z -= L; x.w -= L;
    o4[v4] = x;
  }
}

extern "C" void kernel_launch(void* const* d_in, const int* in_sizes, int n_in,
                              void* d_out, int out_size, void* d_ws, size_t ws_size,
                              hipStream_t stream) {
  const float* x     = (const float*)d_in[0];
  const float* W_all = (const float*)d_in[1];
  const float* Wg    = (const float*)d_in[2];
  const float* bg    = (const float*)d_in[3];
  const float* Ws    = (const float*)d_in[4];
  const float* bs    = (const float*)d_in[5];
  const int*   ei    = (const int*)d_in[6];
  const int*   etp   = (const int*)d_in[7];
  float* out = (float*)d_out;
  float* ws  = (float*)d_ws;

  int*   mcount  = (int*)(ws + WS_MC);
  int*   cnt     = (int*)(ws + WS_CNT);
  float* h0accT  = ws + WS_H0T;
  float* u       = ws + WS_U;
  int*   matches = (int*)(ws + WS_MAT);
  float* pm      = ws + WS_PM;
  float* ps      = ws + WS_PS;

  // zero mcount + cnt + h0accT (contiguous prefix)
  hipMemsetAsync(d_ws, 0, 4176 * sizeof(float), stream);

  dim3 gscan(NB, 16);
  k_scan<<<gscan, 256, 0, stream>>>(ei, etp, mcount, cnt, matches);
  k_u<<<NB, 256, 0, stream>>>(x, mcount, cnt, matches, u);
  dim3 gh0(NR + 1, 8);
  k_h0w<<<gh0, 256, 0, stream>>>(W_all, u, h0accT);
  k_logits<<<NTG + NTS, 1024, 0, stream>>>(Wg, bg, Ws, bs, h0accT, out, pm, ps);
  dim3 gfin(FTG + FTS, NB);
  k_fin<<<gfin, 256, 0, stream>>>(pm, ps, out);
}